// Round 2
// baseline (363.559 us; speedup 1.0000x reference)
//
#include <hip/hip_runtime.h>

// Per-pixel attention over 32 "boxes" (all fp32):
//   q,k,v: [32 box][4 batch][64 ch][6400 pix]
//   scores[i,j] = <q[i,:,p], k[j,:,p]> / 8 ; w = softmax_j ; out[i,c,p] = sum_j w[i,j] v[j,c,p]
// One block = (batch b, 32-pixel tile). Thread t owns (pixel = t&31, queries i0 = (t>>5)*2).
// Full 32-wide score row per (query,pixel) in registers -> softmax in-lane, no shuffles.
// K/V chunks staged to LDS transposed [c][p][j], row stride 36 floats:
//   reads  : ds_read_b128 over j, bank-conflict-minimum (start classes 4*(pp+jg) mod 32)
//   writes : b32, 4-way conflict, but writes are 1/16 of read traffic -> negligible
// T14 async-stage: next chunk's global loads issued before compute, LDS-write after barrier.

#define NBOX    32
#define NBATCH  4
#define CH      64
#define HW      6400
#define PIX     32
#define CC      8            // channels per LDS chunk
#define NCHUNK  (CH / CC)    // 8
#define IB      2            // queries per thread
#define NT      512
#define LPJ     36           // LDS row stride in floats (32 j + 4 pad, keeps 16B align)

__device__ __forceinline__ void stage_load(const float* __restrict__ src, int b, int c0,
                                           int p0, int t, float4 r[4]) {
#pragma unroll
    for (int u = 0; u < 4; ++u) {
        int f  = u * NT + t;          // 0..2047
        int pg = f & 7;               // pixel group of 4
        int j  = (f >> 3) & 31;       // box
        int c  = f >> 8;              // 0..7 channel within chunk
        const float* g = src + ((size_t)((j * NBATCH + b) * CH + (c0 + c)) * HW + p0 + pg * 4);
        r[u] = *reinterpret_cast<const float4*>(g);
    }
}

__device__ __forceinline__ void stage_write(float* lds, int t, const float4 r[4]) {
#pragma unroll
    for (int u = 0; u < 4; ++u) {
        int f  = u * NT + t;
        int pg = f & 7;
        int j  = (f >> 3) & 31;
        int c  = f >> 8;
        float* d = &lds[(c * PIX + pg * 4) * LPJ + j];
        d[0 * LPJ] = r[u].x;
        d[1 * LPJ] = r[u].y;
        d[2 * LPJ] = r[u].z;
        d[3 * LPJ] = r[u].w;
    }
}

__global__ __launch_bounds__(NT, 4)
void box_attn_kernel(const float* __restrict__ q,
                     const float* __restrict__ k,
                     const float* __restrict__ v,
                     float* __restrict__ out) {
    __shared__ float lds[CC * PIX * LPJ];   // 36 KiB

    const int t    = threadIdx.x;
    const int bid  = blockIdx.x;
    const int b    = bid / (HW / PIX);
    const int tile = bid % (HW / PIX);
    const int p0   = tile * PIX;

    const int pp = t & (PIX - 1);
    const int i0 = (t >> 5) * IB;   // first of this thread's 2 queries

    float s[IB][NBOX];
#pragma unroll
    for (int a = 0; a < IB; ++a)
#pragma unroll
        for (int j = 0; j < NBOX; ++j) s[a][j] = 0.f;

    float4 rb[4];

    // ---------------- Phase 1: scores = (Q K^T) / 8 ----------------
    stage_load(k, b, 0, p0, t, rb);
    stage_write(lds, t, rb);
#pragma unroll
    for (int ch = 0; ch < NCHUNK; ++ch) {
        const int c0 = ch * CC;
        if (ch + 1 < NCHUNK) stage_load(k, b, c0 + CC, p0, t, rb);   // T14: issue early

        // this thread's Q slice for the chunk (each q element read exactly once)
        float qf[IB][CC];
#pragma unroll
        for (int a = 0; a < IB; ++a)
#pragma unroll
            for (int c = 0; c < CC; ++c)
                qf[a][c] = q[(size_t)(((i0 + a) * NBATCH + b) * CH + (c0 + c)) * HW + p0 + pp]
                           * 0.125f;   // fold 1/sqrt(64)

        __syncthreads();   // chunk ch visible in LDS
#pragma unroll
        for (int c = 0; c < CC; ++c) {
#pragma unroll
            for (int jg = 0; jg < 8; ++jg) {
                float4 kv = *reinterpret_cast<const float4*>(&lds[(c * PIX + pp) * LPJ + jg * 4]);
#pragma unroll
                for (int a = 0; a < IB; ++a) {
                    s[a][jg * 4 + 0] = fmaf(qf[a][c], kv.x, s[a][jg * 4 + 0]);
                    s[a][jg * 4 + 1] = fmaf(qf[a][c], kv.y, s[a][jg * 4 + 1]);
                    s[a][jg * 4 + 2] = fmaf(qf[a][c], kv.z, s[a][jg * 4 + 2]);
                    s[a][jg * 4 + 3] = fmaf(qf[a][c], kv.w, s[a][jg * 4 + 3]);
                }
            }
        }
        __syncthreads();   // all reads of chunk ch done
        if (ch + 1 < NCHUNK) stage_write(lds, t, rb);   // T14: write late
    }

    // ---------------- softmax over j (in-register) ----------------
    stage_load(v, b, 0, p0, t, rb);   // overlap V chunk-0 fetch with softmax
#pragma unroll
    for (int a = 0; a < IB; ++a) {
        float m = s[a][0];
#pragma unroll
        for (int j = 1; j < NBOX; ++j) m = fmaxf(m, s[a][j]);
        float sum = 0.f;
#pragma unroll
        for (int j = 0; j < NBOX; ++j) { float e = __expf(s[a][j] - m); s[a][j] = e; sum += e; }
        float inv = 1.f / sum;
#pragma unroll
        for (int j = 0; j < NBOX; ++j) s[a][j] *= inv;
    }

    // ---------------- Phase 2: out = W V ----------------
    stage_write(lds, t, rb);   // V chunk 0 (phase-1 trailing barrier protects LDS)
#pragma unroll
    for (int ch = 0; ch < NCHUNK; ++ch) {
        const int c0 = ch * CC;
        if (ch + 1 < NCHUNK) stage_load(v, b, c0 + CC, p0, t, rb);

        __syncthreads();
        float acc[IB][CC];
#pragma unroll
        for (int a = 0; a < IB; ++a)
#pragma unroll
            for (int c = 0; c < CC; ++c) acc[a][c] = 0.f;
#pragma unroll
        for (int c = 0; c < CC; ++c) {
#pragma unroll
            for (int jg = 0; jg < 8; ++jg) {
                float4 vv = *reinterpret_cast<const float4*>(&lds[(c * PIX + pp) * LPJ + jg * 4]);
#pragma unroll
                for (int a = 0; a < IB; ++a) {
                    acc[a][c] = fmaf(s[a][jg * 4 + 0], vv.x, acc[a][c]);
                    acc[a][c] = fmaf(s[a][jg * 4 + 1], vv.y, acc[a][c]);
                    acc[a][c] = fmaf(s[a][jg * 4 + 2], vv.z, acc[a][c]);
                    acc[a][c] = fmaf(s[a][jg * 4 + 3], vv.w, acc[a][c]);
                }
            }
        }
#pragma unroll
        for (int a = 0; a < IB; ++a)
#pragma unroll
            for (int c = 0; c < CC; ++c)
                out[(size_t)(((i0 + a) * NBATCH + b) * CH + (c0 + c)) * HW + p0 + pp] = acc[a][c];

        __syncthreads();
        if (ch + 1 < NCHUNK) stage_write(lds, t, rb);
    }
}

extern "C" void kernel_launch(void* const* d_in, const int* in_sizes, int n_in,
                              void* d_out, int out_size, void* d_ws, size_t ws_size,
                              hipStream_t stream) {
    const float* q = (const float*)d_in[0];
    const float* k = (const float*)d_in[1];
    const float* v = (const float*)d_in[2];
    float* o = (float*)d_out;
    dim3 grid(NBATCH * (HW / PIX));   // 800 blocks
    box_attn_kernel<<<grid, NT, 0, stream>>>(q, k, v, o);
}

// Round 3
// 346.571 us; speedup vs baseline: 1.0490x; 1.0490x over previous
//
#include <hip/hip_runtime.h>

// Per-pixel attention over 32 "boxes" (all fp32):
//   q,k,v: [32 box][4 batch][64 ch][6400 pix]
//   scores[i,j] = <q[i,:,p], k[j,:,p]> / 8 ; w = softmax_j ; out[i,c,p] = sum_j w[i,j] v[j,c,p]
// One block = (batch b, 32-pixel tile). Thread t owns (pixel = t&31, queries i0 = (t>>5)*2).
// Full 32-wide score row per (query,pixel) in registers -> softmax in-lane, no shuffles.
//
// R3 change vs R2: the R2 kernel spilled (~250 MB scratch write traffic, VGPR capped at 64,
// VALUBusy 20%). Chunk shrunk CC=8 -> 4 so in-flight staging regs drop 16->8 and qf 16->8;
// true usage ~110 regs fits the __launch_bounds__(512,4) budget of 128 -> no spill,
// 4 waves/SIMD. PIX stays 32: 128B-aligned global segments (16-pixel tiles would split
// 128B cache lines across blocks/XCDs and ~2x the fetch).
//
// LDS [c][p][j], row stride 36 floats: b128 reads over j are conflict-balanced
// (start banks 4*(pp+jg) mod 32 tile all 32 banks exactly once; 4 rows/bank over the
// 4-cycle minimum of a 512B wave read). Staging b32 writes have mild conflicts; write
// traffic is 1/16 of reads.

#define NBOX    32
#define NBATCH  4
#define CH      64
#define HW      6400
#define PIX     32
#define CC      4            // channels per LDS chunk (small => low reg pressure)
#define NCHUNK  (CH / CC)    // 16
#define IB      2            // queries per thread
#define NT      512
#define LPJ     36           // LDS row stride in floats (32 j + 4 pad, keeps 16B align)

__device__ __forceinline__ void stage_load(const float* __restrict__ src, int b, int c0,
                                           int p0, int t, float4 r[2]) {
#pragma unroll
    for (int u = 0; u < 2; ++u) {
        int f  = u * NT + t;          // 0..1023
        int pg = f & 7;               // pixel group of 4 (pixels pg*4..pg*4+3)
        int j  = (f >> 3) & 31;       // box
        int c  = f >> 8;              // 0..3 channel within chunk
        const float* g = src + ((size_t)((j * NBATCH + b) * CH + (c0 + c)) * HW + p0 + pg * 4);
        r[u] = *reinterpret_cast<const float4*>(g);
    }
}

__device__ __forceinline__ void stage_write(float* lds, int t, const float4 r[2]) {
#pragma unroll
    for (int u = 0; u < 2; ++u) {
        int f  = u * NT + t;
        int pg = f & 7;
        int j  = (f >> 3) & 31;
        int c  = f >> 8;
        float* d = &lds[(c * PIX + pg * 4) * LPJ + j];
        d[0 * LPJ] = r[u].x;
        d[1 * LPJ] = r[u].y;
        d[2 * LPJ] = r[u].z;
        d[3 * LPJ] = r[u].w;
    }
}

__global__ __launch_bounds__(NT, 4)
void box_attn_kernel(const float* __restrict__ q,
                     const float* __restrict__ k,
                     const float* __restrict__ v,
                     float* __restrict__ out) {
    __shared__ float lds[CC * PIX * LPJ];   // 18.4 KiB

    const int t    = threadIdx.x;
    const int bid  = blockIdx.x;
    const int b    = bid / (HW / PIX);
    const int tile = bid % (HW / PIX);
    const int p0   = tile * PIX;

    const int pp = t & (PIX - 1);
    const int i0 = (t >> 5) * IB;   // first of this thread's 2 queries

    float s[IB][NBOX];
#pragma unroll
    for (int a = 0; a < IB; ++a)
#pragma unroll
        for (int j = 0; j < NBOX; ++j) s[a][j] = 0.f;

    float4 rb[2];

    // ---------------- Phase 1: scores = (Q K^T) / 8 ----------------
    stage_load(k, b, 0, p0, t, rb);
    stage_write(lds, t, rb);
#pragma unroll
    for (int ch = 0; ch < NCHUNK; ++ch) {
        const int c0 = ch * CC;
        if (ch + 1 < NCHUNK) stage_load(k, b, c0 + CC, p0, t, rb);   // T14: issue early

        // this thread's Q slice for the chunk (each q element read exactly once)
        float qf[IB][CC];
#pragma unroll
        for (int a = 0; a < IB; ++a)
#pragma unroll
            for (int c = 0; c < CC; ++c)
                qf[a][c] = q[(size_t)(((i0 + a) * NBATCH + b) * CH + (c0 + c)) * HW + p0 + pp]
                           * 0.125f;   // fold 1/sqrt(64)

        __syncthreads();   // chunk ch visible in LDS
#pragma unroll
        for (int c = 0; c < CC; ++c) {
#pragma unroll
            for (int jg = 0; jg < 8; ++jg) {
                float4 kv = *reinterpret_cast<const float4*>(&lds[(c * PIX + pp) * LPJ + jg * 4]);
#pragma unroll
                for (int a = 0; a < IB; ++a) {
                    s[a][jg * 4 + 0] = fmaf(qf[a][c], kv.x, s[a][jg * 4 + 0]);
                    s[a][jg * 4 + 1] = fmaf(qf[a][c], kv.y, s[a][jg * 4 + 1]);
                    s[a][jg * 4 + 2] = fmaf(qf[a][c], kv.z, s[a][jg * 4 + 2]);
                    s[a][jg * 4 + 3] = fmaf(qf[a][c], kv.w, s[a][jg * 4 + 3]);
                }
            }
        }
        __syncthreads();   // all reads of chunk ch done
        if (ch + 1 < NCHUNK) stage_write(lds, t, rb);   // T14: write late
    }

    // ---------------- softmax over j (in-register) ----------------
    stage_load(v, b, 0, p0, t, rb);   // overlap V chunk-0 fetch with softmax
#pragma unroll
    for (int a = 0; a < IB; ++a) {
        float m = s[a][0];
#pragma unroll
        for (int j = 1; j < NBOX; ++j) m = fmaxf(m, s[a][j]);
        float sum = 0.f;
#pragma unroll
        for (int j = 0; j < NBOX; ++j) { float e = __expf(s[a][j] - m); s[a][j] = e; sum += e; }
        float inv = 1.f / sum;
#pragma unroll
        for (int j = 0; j < NBOX; ++j) s[a][j] *= inv;
    }

    // ---------------- Phase 2: out = W V ----------------
    stage_write(lds, t, rb);   // V chunk 0 (phase-1 trailing barrier protects LDS)
#pragma unroll
    for (int ch = 0; ch < NCHUNK; ++ch) {
        const int c0 = ch * CC;
        if (ch + 1 < NCHUNK) stage_load(v, b, c0 + CC, p0, t, rb);

        __syncthreads();
        float acc[IB][CC];
#pragma unroll
        for (int a = 0; a < IB; ++a)
#pragma unroll
            for (int c = 0; c < CC; ++c) acc[a][c] = 0.f;
#pragma unroll
        for (int c = 0; c < CC; ++c) {
#pragma unroll
            for (int jg = 0; jg < 8; ++jg) {
                float4 vv = *reinterpret_cast<const float4*>(&lds[(c * PIX + pp) * LPJ + jg * 4]);
#pragma unroll
                for (int a = 0; a < IB; ++a) {
                    acc[a][c] = fmaf(s[a][jg * 4 + 0], vv.x, acc[a][c]);
                    acc[a][c] = fmaf(s[a][jg * 4 + 1], vv.y, acc[a][c]);
                    acc[a][c] = fmaf(s[a][jg * 4 + 2], vv.z, acc[a][c]);
                    acc[a][c] = fmaf(s[a][jg * 4 + 3], vv.w, acc[a][c]);
                }
            }
        }
#pragma unroll
        for (int a = 0; a < IB; ++a)
#pragma unroll
            for (int c = 0; c < CC; ++c)
                out[(size_t)(((i0 + a) * NBATCH + b) * CH + (c0 + c)) * HW + p0 + pp] = acc[a][c];

        __syncthreads();
        if (ch + 1 < NCHUNK) stage_write(lds, t, rb);
    }
}

extern "C" void kernel_launch(void* const* d_in, const int* in_sizes, int n_in,
                              void* d_out, int out_size, void* d_ws, size_t ws_size,
                              hipStream_t stream) {
    const float* q = (const float*)d_in[0];
    const float* k = (const float*)d_in[1];
    const float* v = (const float*)d_in[2];
    float* o = (float*)d_out;
    dim3 grid(NBATCH * (HW / PIX));   // 800 blocks
    box_attn_kernel<<<grid, NT, 0, stream>>>(q, k, v, o);
}

// Round 4
// 251.256 us; speedup vs baseline: 1.4470x; 1.3794x over previous
//
#include <hip/hip_runtime.h>

// Per-pixel attention over 32 "boxes" (all fp32):
//   q,k,v: [32 box][4 batch][64 ch][6400 pix]
//   scores[i,j] = <q[i,:,p], k[j,:,p]> / 8 ; w = softmax_j ; out[i,c,p] = sum_j w[i,j] v[j,c,p]
// One block = (batch b, 32-pixel tile). Thread t owns (pixel = t&31, queries i0 = (t>>5)*2).
// Full 32-wide score row per (query,pixel) in registers -> softmax in-lane, no shuffles.
//
// R4 change vs R3: __launch_bounds__(512,4) was interpreted as 4 blocks/CU = 8 waves/SIMD
// -> VGPR cap 64 (rocprof: VGPR_Count=64) while live state is ~110 -> rb/qf prefetch regs
// spilled to scratch (~230 MB excess WRITE_SIZE, T14 latency hiding destroyed, VALUBusy 20%).
// Now __launch_bounds__(512,2): VGPR cap >=128 under either arg interpretation -> no spill.
//
// LDS [c][p][j], row stride 36 floats: b128 reads over j are conflict-balanced
// (start banks 4*(pp+jg) mod 32 tile all 32 banks; 4-way on staging b32 writes, 1/16 of
// read traffic -> ~12% LDS overhead, secondary).

#define NBOX    32
#define NBATCH  4
#define CH      64
#define HW      6400
#define PIX     32
#define CC      4            // channels per LDS chunk (small => low reg pressure)
#define NCHUNK  (CH / CC)    // 16
#define IB      2            // queries per thread
#define NT      512
#define LPJ     36           // LDS row stride in floats (32 j + 4 pad, keeps 16B align)

__device__ __forceinline__ void stage_load(const float* __restrict__ src, int b, int c0,
                                           int p0, int t, float4 r[2]) {
#pragma unroll
    for (int u = 0; u < 2; ++u) {
        int f  = u * NT + t;          // 0..1023
        int pg = f & 7;               // pixel group of 4 (pixels pg*4..pg*4+3)
        int j  = (f >> 3) & 31;       // box
        int c  = f >> 8;              // 0..3 channel within chunk
        const float* g = src + ((size_t)((j * NBATCH + b) * CH + (c0 + c)) * HW + p0 + pg * 4);
        r[u] = *reinterpret_cast<const float4*>(g);
    }
}

__device__ __forceinline__ void stage_write(float* lds, int t, const float4 r[2]) {
#pragma unroll
    for (int u = 0; u < 2; ++u) {
        int f  = u * NT + t;
        int pg = f & 7;
        int j  = (f >> 3) & 31;
        int c  = f >> 8;
        float* d = &lds[(c * PIX + pg * 4) * LPJ + j];
        d[0 * LPJ] = r[u].x;
        d[1 * LPJ] = r[u].y;
        d[2 * LPJ] = r[u].z;
        d[3 * LPJ] = r[u].w;
    }
}

__global__ __launch_bounds__(NT, 2)
void box_attn_kernel(const float* __restrict__ q,
                     const float* __restrict__ k,
                     const float* __restrict__ v,
                     float* __restrict__ out) {
    __shared__ float lds[CC * PIX * LPJ];   // 18.4 KiB

    const int t    = threadIdx.x;
    const int bid  = blockIdx.x;
    const int b    = bid / (HW / PIX);
    const int tile = bid % (HW / PIX);
    const int p0   = tile * PIX;

    const int pp = t & (PIX - 1);
    const int i0 = (t >> 5) * IB;   // first of this thread's 2 queries

    float s[IB][NBOX];
#pragma unroll
    for (int a = 0; a < IB; ++a)
#pragma unroll
        for (int j = 0; j < NBOX; ++j) s[a][j] = 0.f;

    float4 rb[2];

    // ---------------- Phase 1: scores = (Q K^T) / 8 ----------------
    stage_load(k, b, 0, p0, t, rb);
    stage_write(lds, t, rb);
#pragma unroll
    for (int ch = 0; ch < NCHUNK; ++ch) {
        const int c0 = ch * CC;
        if (ch + 1 < NCHUNK) stage_load(k, b, c0 + CC, p0, t, rb);   // T14: issue early

        // this thread's Q slice for the chunk (each q element read exactly once)
        float qf[IB][CC];
#pragma unroll
        for (int a = 0; a < IB; ++a)
#pragma unroll
            for (int c = 0; c < CC; ++c)
                qf[a][c] = q[(size_t)(((i0 + a) * NBATCH + b) * CH + (c0 + c)) * HW + p0 + pp]
                           * 0.125f;   // fold 1/sqrt(64)

        __syncthreads();   // chunk ch visible in LDS
#pragma unroll
        for (int c = 0; c < CC; ++c) {
#pragma unroll
            for (int jg = 0; jg < 8; ++jg) {
                float4 kv = *reinterpret_cast<const float4*>(&lds[(c * PIX + pp) * LPJ + jg * 4]);
#pragma unroll
                for (int a = 0; a < IB; ++a) {
                    s[a][jg * 4 + 0] = fmaf(qf[a][c], kv.x, s[a][jg * 4 + 0]);
                    s[a][jg * 4 + 1] = fmaf(qf[a][c], kv.y, s[a][jg * 4 + 1]);
                    s[a][jg * 4 + 2] = fmaf(qf[a][c], kv.z, s[a][jg * 4 + 2]);
                    s[a][jg * 4 + 3] = fmaf(qf[a][c], kv.w, s[a][jg * 4 + 3]);
                }
            }
        }
        __syncthreads();   // all reads of chunk ch done
        if (ch + 1 < NCHUNK) stage_write(lds, t, rb);   // T14: write late
    }

    // ---------------- softmax over j (in-register) ----------------
    stage_load(v, b, 0, p0, t, rb);   // overlap V chunk-0 fetch with softmax
#pragma unroll
    for (int a = 0; a < IB; ++a) {
        float m = s[a][0];
#pragma unroll
        for (int j = 1; j < NBOX; ++j) m = fmaxf(m, s[a][j]);
        float sum = 0.f;
#pragma unroll
        for (int j = 0; j < NBOX; ++j) { float e = __expf(s[a][j] - m); s[a][j] = e; sum += e; }
        float inv = 1.f / sum;
#pragma unroll
        for (int j = 0; j < NBOX; ++j) s[a][j] *= inv;
    }

    // ---------------- Phase 2: out = W V ----------------
    stage_write(lds, t, rb);   // V chunk 0 (phase-1 trailing barrier protects LDS)
#pragma unroll
    for (int ch = 0; ch < NCHUNK; ++ch) {
        const int c0 = ch * CC;
        if (ch + 1 < NCHUNK) stage_load(v, b, c0 + CC, p0, t, rb);

        __syncthreads();
        float acc[IB][CC];
#pragma unroll
        for (int a = 0; a < IB; ++a)
#pragma unroll
            for (int c = 0; c < CC; ++c) acc[a][c] = 0.f;
#pragma unroll
        for (int c = 0; c < CC; ++c) {
#pragma unroll
            for (int jg = 0; jg < 8; ++jg) {
                float4 vv = *reinterpret_cast<const float4*>(&lds[(c * PIX + pp) * LPJ + jg * 4]);
#pragma unroll
                for (int a = 0; a < IB; ++a) {
                    acc[a][c] = fmaf(s[a][jg * 4 + 0], vv.x, acc[a][c]);
                    acc[a][c] = fmaf(s[a][jg * 4 + 1], vv.y, acc[a][c]);
                    acc[a][c] = fmaf(s[a][jg * 4 + 2], vv.z, acc[a][c]);
                    acc[a][c] = fmaf(s[a][jg * 4 + 3], vv.w, acc[a][c]);
                }
            }
        }
#pragma unroll
        for (int a = 0; a < IB; ++a)
#pragma unroll
            for (int c = 0; c < CC; ++c)
                out[(size_t)(((i0 + a) * NBATCH + b) * CH + (c0 + c)) * HW + p0 + pp] = acc[a][c];

        __syncthreads();
        if (ch + 1 < NCHUNK) stage_write(lds, t, rb);
    }
}

extern "C" void kernel_launch(void* const* d_in, const int* in_sizes, int n_in,
                              void* d_out, int out_size, void* d_ws, size_t ws_size,
                              hipStream_t stream) {
    const float* q = (const float*)d_in[0];
    const float* k = (const float*)d_in[1];
    const float* v = (const float*)d_in[2];
    float* o = (float*)d_out;
    dim3 grid(NBATCH * (HW / PIX));   // 800 blocks
    box_attn_kernel<<<grid, NT, 0, stream>>>(q, k, v, o);
}